// Round 4
// baseline (1388.177 us; speedup 1.0000x reference)
//
#include <hip/hip_runtime.h>
#include <stdint.h>

#define HID 512
#define BM 128
#define BK 16
#define KSTEPS 32

typedef __attribute__((ext_vector_type(8))) short bf16x8;
typedef __attribute__((ext_vector_type(4))) short short4v;
typedef __attribute__((ext_vector_type(4))) float f32x4;
typedef __attribute__((ext_vector_type(16))) float f32x16;

#define WAITB(N) asm volatile("s_waitcnt lgkmcnt(0) vmcnt(" #N ")" ::: "memory")

__device__ __forceinline__ unsigned short f2bf_rne(float f) {
  unsigned u = __float_as_uint(f);
  unsigned r = u + 0x7fffu + ((u >> 16) & 1u);
  return (unsigned short)(r >> 16);
}

__device__ __forceinline__ void gload_lds16(const void* g, void* l) {
  auto gp = reinterpret_cast<const __attribute__((address_space(1))) unsigned int*>(
      (unsigned long long)(uintptr_t)g);
  auto lp = reinterpret_cast<__attribute__((address_space(3))) unsigned int*>(
      (unsigned int)(uintptr_t)l);
  __builtin_amdgcn_global_load_lds(gp, lp, 16, 0, 0);
}

// W [512 k][512 n] fp32 -> packed hi/lo bf16, tile layout [x][ks][c][256 n][8 k]
__global__ void trans_split_kernel(const float* __restrict__ W,
                                   short* __restrict__ Bth, short* __restrict__ Btl) {
  int id = blockIdx.x * 256 + threadIdx.x;
  int e = id & 7, nl = (id >> 3) & 255, c = (id >> 11) & 1, ks = (id >> 12) & 31,
      x = (id >> 17) & 1;
  int n = x * 256 + nl, k = ks * 16 + c * 8 + e;
  float w = W[(size_t)k * 512 + n];
  unsigned short hi = f2bf_rne(w);
  float rem = w - __uint_as_float(((unsigned)hi) << 16);
  unsigned short lo = f2bf_rne(rem);
  Bth[id] = (short)hi;
  Btl[id] = (short)lo;
}

__global__ void init_out_kernel(float* __restrict__ out, const float* __restrict__ p3b, int n) {
  int id = blockIdx.x * 256 + threadIdx.x;
  if (id < n) out[id] = p3b[0];
}

// MODE: 0 = C = relu(A@Bt^T + bias)
//       1 = C = relu(A@Bt^T + bias) + A               (residual)
//       2 = C = A@Bt^T (+ bias if non-null, no relu)  (U/V projections)
//       3 = score[row] += dot(relu(relu(U[s]+V[d])@Bt^T + bias), p3)
// BNT: 256 -> grid.x=2 via swizzle, 512 threads; 512 -> full width, 1024 threads
template <int MODE, int BNT>
__global__ __launch_bounds__(BNT * 2, 4) void gemm_kernel(
    const float* A, const float* A2,
    const short* __restrict__ Bth, const short* __restrict__ Btl,
    const float* __restrict__ bias,
    const int* __restrict__ isrc, const int* __restrict__ idst,
    const float* __restrict__ p3,
    float* Cout, float* __restrict__ score, int M) {
  constexpr int WN = BNT / 64;                 // waves along N
  constexpr int AH = 0;                        // [c][128][8]
  constexpr int AL = 2048;
  constexpr int BH = 4096;                     // [x][c][256][8]
  constexpr int BL = 4096 + BNT * 16;
  constexpr int BUFSZ = 4096 + 2 * BNT * 16;   // shorts

  __shared__ __align__(16) short lds[3][BUFSZ];

  const int tid = threadIdx.x;
  const int lane = tid & 63;
  const int wid = tid >> 6;
  const int wr = wid / WN, wc = wid % WN;      // per-wave 64 rows x 64 cols
  const int ln31 = lane & 31, lh2 = lane >> 5;

  // ---- XCD-paired block swizzle ----
  const int yb = (M + BM - 1) >> 7;
  const int px = (yb + 7) >> 3;
  int xblk, y;
  {
    int g = blockIdx.x;
    int c8 = g & 7, idx = g >> 3;
    if (BNT == 256) { xblk = idx & 1; y = c8 * px + (idx >> 1); }
    else            { xblk = 0;       y = c8 * px + idx; }
  }
  if (y >= yb) return;
  const int m0 = y * BM;
  const int n0 = xblk * BNT;

  // ---- A staging mapping: thread t<512 owns row t>>2, float-quad t&3 ----
  const int rowA = tid >> 2;
  const int cA = tid & 3;
  const float* gA = nullptr;
  const float* gA2 = nullptr;
  if (tid < 512) {
    if constexpr (MODE == 3) {
      int e = m0 + rowA; if (e > M - 1) e = M - 1;
      gA  = A  + (size_t)isrc[e] * HID + cA * 4;
      gA2 = A2 + (size_t)idst[e] * HID + cA * 4;
    } else {
      int r = m0 + rowA; if (r > M - 1) r = M - 1;
      gA = A + (size_t)r * HID + cA * 4;
    }
  }

  f32x16 acc[2][2];
#pragma unroll
  for (int i = 0; i < 2; ++i)
#pragma unroll
    for (int j = 0; j < 2; ++j)
#pragma unroll
      for (int r = 0; r < 16; ++r) acc[i][j][r] = 0.f;

  auto stageB = [&](int ks, short* buf) {
    if constexpr (BNT == 256) {
      const size_t toff = (size_t)(xblk * 32 + ks) * 4096;
      gload_lds16(Bth + toff + tid * 8, buf + BH + tid * 8);
      gload_lds16(Btl + toff + tid * 8, buf + BL + tid * 8);
    } else {
      const int xp = tid >> 9, tt = tid & 511;
      const size_t toff = (size_t)(xp * 32 + ks) * 4096 + tt * 8;
      gload_lds16(Bth + toff, buf + BH + tid * 8);
      gload_lds16(Btl + toff, buf + BL + tid * 8);
    }
  };
  auto loadA = [&](int ks, f32x4& a, f32x4& v) {
    if (tid < 512) {
      a = *reinterpret_cast<const f32x4*>(gA + ks * BK);
      if constexpr (MODE == 3) v = *reinterpret_cast<const f32x4*>(gA2 + ks * BK);
    }
  };
  auto writeA = [&](const f32x4& a, const f32x4& v, short* buf) {
    if (tid < 512) {
      float f[4];
#pragma unroll
      for (int q = 0; q < 4; ++q) {
        f[q] = a[q];
        if constexpr (MODE == 3) f[q] = fmaxf(f[q] + v[q], 0.f);
      }
      short4v h4, l4;
#pragma unroll
      for (int q = 0; q < 4; ++q) {
        unsigned ua = __float_as_uint(f[q]);
        h4[q] = (short)(ua >> 16);
        float rem = f[q] - __uint_as_float(ua & 0xffff0000u);
        l4[q] = (short)(__float_as_uint(rem) >> 16);
      }
      const int doff = (cA >> 1) * 1024 + rowA * 8 + (cA & 1) * 4;
      *reinterpret_cast<short4v*>(buf + AH + doff) = h4;
      *reinterpret_cast<short4v*>(buf + AL + doff) = l4;
    }
  };
  auto compute = [&](const short* buf) {
    bf16x8 ah[2], al[2], bh[2], bl[2];
#pragma unroll
    for (int i = 0; i < 2; ++i) {
      const int aoff = lh2 * 1024 + (wr * 64 + i * 32 + ln31) * 8;
      ah[i] = *reinterpret_cast<const bf16x8*>(buf + AH + aoff);
      al[i] = *reinterpret_cast<const bf16x8*>(buf + AL + aoff);
    }
#pragma unroll
    for (int j = 0; j < 2; ++j) {
      const int cb = wc * 64 + j * 32 + ln31;
      const int boff = (cb >> 8) * 4096 + lh2 * 2048 + (cb & 255) * 8;
      bh[j] = *reinterpret_cast<const bf16x8*>(buf + BH + boff);
      bl[j] = *reinterpret_cast<const bf16x8*>(buf + BL + boff);
    }
    __builtin_amdgcn_s_setprio(1);
#pragma unroll
    for (int i = 0; i < 2; ++i)
#pragma unroll
      for (int j = 0; j < 2; ++j) {
        acc[i][j] = __builtin_amdgcn_mfma_f32_32x32x16_bf16(ah[i], bh[j], acc[i][j], 0, 0, 0);
        acc[i][j] = __builtin_amdgcn_mfma_f32_32x32x16_bf16(ah[i], bl[j], acc[i][j], 0, 0, 0);
        acc[i][j] = __builtin_amdgcn_mfma_f32_32x32x16_bf16(al[i], bh[j], acc[i][j], 0, 0, 0);
      }
    __builtin_amdgcn_s_setprio(0);
  };

  // counted waits: group size = 2 gload_lds (+ nA A-loads for A-staging threads)
  auto pipe_wait_full = [&]() {
    if constexpr (MODE == 3) {
      WAITB(4);
    } else if constexpr (BNT == 512) {
      if (tid < 512) WAITB(3); else WAITB(2);
    } else {
      WAITB(3);
    }
  };

  f32x4 aA{}, vA{}, aB{}, vB{};

  // ---- prologue: stage 0 and 1, write A(0), one counted barrier ----
  stageB(0, lds[0]);
  {
    f32x4 t{}, tv{};
    loadA(0, t, tv);
    stageB(1, lds[1]);
    loadA(1, aA, vA);
    writeA(t, tv, lds[0]);   // compiler inserts counted vmcnt for t
  }
  pipe_wait_full();
  __builtin_amdgcn_s_barrier();
  __builtin_amdgcn_sched_barrier(0);

  short* bA = lds[0];  // buffer for step ks
  short* bB = lds[1];  // step ks+1 (B staged; A written this iter)
  short* bC = lds[2];  // step ks+2 (staged this iter)

  // ---- main loop: depth-2 pipeline, loads stay in flight across barriers ----
  for (int ks = 0; ks < KSTEPS; ++ks) {
    if (ks + 2 < KSTEPS) {
      stageB(ks + 2, bC);
      loadA(ks + 2, aB, vB);
    }
    compute(bA);
    if (ks + 1 < KSTEPS) {
      writeA(aA, vA, bB);
      if (ks + 2 < KSTEPS) {
        pipe_wait_full();
      } else {
        WAITB(0);
      }
      __builtin_amdgcn_s_barrier();
      __builtin_amdgcn_sched_barrier(0);
      aA = aB; vA = vB;
    }
    short* t = bA; bA = bB; bB = bC; bC = t;
  }

  // ---- epilogue ----
  float bj[2], pj[2];
#pragma unroll
  for (int j = 0; j < 2; ++j) {
    const int gcol = n0 + wc * 64 + j * 32 + ln31;
    if constexpr (MODE == 3) { bj[j] = bias[gcol]; pj[j] = p3[gcol]; }
    else if constexpr (MODE == 2) { bj[j] = bias ? bias[gcol] : 0.f; pj[j] = 0.f; }
    else { bj[j] = bias[gcol]; pj[j] = 0.f; }
  }

  if constexpr (MODE == 3) {
#pragma unroll
    for (int i = 0; i < 2; ++i)
#pragma unroll
      for (int r = 0; r < 16; ++r) {
        float pS = 0.f;
#pragma unroll
        for (int j = 0; j < 2; ++j)
          pS += fmaxf(acc[i][j][r] + bj[j], 0.f) * pj[j];
        pS += __shfl_xor(pS, 1);
        pS += __shfl_xor(pS, 2);
        pS += __shfl_xor(pS, 4);
        pS += __shfl_xor(pS, 8);
        pS += __shfl_xor(pS, 16);
        const int row = m0 + wr * 64 + i * 32 + (r & 3) + 8 * (r >> 2) + 4 * lh2;
        if (ln31 == 0 && row < M) atomicAdd(&score[row], pS);
      }
  } else {
#pragma unroll
    for (int i = 0; i < 2; ++i)
#pragma unroll
      for (int j = 0; j < 2; ++j) {
        const int gcol = n0 + wc * 64 + j * 32 + ln31;
#pragma unroll
        for (int r = 0; r < 16; ++r) {
          const int row = m0 + wr * 64 + i * 32 + (r & 3) + 8 * (r >> 2) + 4 * lh2;
          if (row < M) {
            float v = acc[i][j][r];
            if constexpr (MODE == 2) {
              v += bj[j];
            } else {
              v = fmaxf(v + bj[j], 0.f);
            }
            if constexpr (MODE == 1) v += A[(size_t)row * HID + gcol];
            Cout[(size_t)row * HID + gcol] = v;
          }
        }
      }
  }
}

extern "C" void kernel_launch(void* const* d_in, const int* in_sizes, int n_in,
                              void* d_out, int out_size, void* d_ws, size_t ws_size,
                              hipStream_t stream) {
  (void)n_in; (void)out_size; (void)ws_size;
  const float* x      = (const float*)d_in[0];
  const int* pos_src  = (const int*)d_in[1];
  const int* pos_dst  = (const int*)d_in[2];
  const int* neg_src  = (const int*)d_in[3];
  const int* neg_dst  = (const int*)d_in[4];
  const float* W1 = (const float*)d_in[5];
  const float* b1 = (const float*)d_in[6];
  const float* W2 = (const float*)d_in[7];
  const float* b2 = (const float*)d_in[8];
  const float* Wo = (const float*)d_in[9];
  const float* bo = (const float*)d_in[10];
  const float* P1w = (const float*)d_in[11];
  const float* P1b = (const float*)d_in[12];
  const float* P2w = (const float*)d_in[13];
  const float* P2b = (const float*)d_in[14];
  const float* P3w = (const float*)d_in[15];
  const float* P3b = (const float*)d_in[16];

  const int N_NODES = in_sizes[0] / HID;  // 100000
  const int E = in_sizes[1];              // 100000
  float* out = (float*)d_out;

  char* ws = (char*)d_ws;
  const size_t actBytes = (size_t)N_NODES * HID * sizeof(float);
  float* buf0 = (float*)ws;                 // h1 -> h -> V (in place, BNT=512 variant)
  float* buf1 = (float*)(ws + actBytes);    // h2 -> U
  short* wp = (short*)(ws + 2 * actBytes);
  short* W1th = wp; wp += 512 * 512;
  short* W1tl = wp; wp += 512 * 512;
  short* W2th = wp; wp += 512 * 512;
  short* W2tl = wp; wp += 512 * 512;
  short* Woth = wp; wp += 512 * 512;
  short* Wotl = wp; wp += 512 * 512;
  short* PTth = wp; wp += 512 * 512;   // P1w rows 0..511 (src half)
  short* PTtl = wp; wp += 512 * 512;
  short* PBth = wp; wp += 512 * 512;   // P1w rows 512..1023 (dst half)
  short* PBtl = wp; wp += 512 * 512;
  short* P2th = wp; wp += 512 * 512;
  short* P2tl = wp; wp += 512 * 512;

  trans_split_kernel<<<1024, 256, 0, stream>>>(W1, W1th, W1tl);
  trans_split_kernel<<<1024, 256, 0, stream>>>(W2, W2th, W2tl);
  trans_split_kernel<<<1024, 256, 0, stream>>>(Wo, Woth, Wotl);
  trans_split_kernel<<<1024, 256, 0, stream>>>(P1w, PTth, PTtl);
  trans_split_kernel<<<1024, 256, 0, stream>>>(P1w + (size_t)512 * 512, PBth, PBtl);
  trans_split_kernel<<<1024, 256, 0, stream>>>(P2w, P2th, P2tl);
  init_out_kernel<<<(2 * E + 255) / 256, 256, 0, stream>>>(out, P3b, 2 * E);

  const int ybN = (N_NODES + BM - 1) / BM;
  const int pxN = (ybN + 7) / 8;
  const int ybE = (E + BM - 1) / BM;
  const int pxE = (ybE + 7) / 8;
  dim3 g256N(8 * pxN * 2), g512N(8 * pxN), g256E(8 * pxE * 2);
  dim3 b512(512), b1024(1024);

  // encoder
  gemm_kernel<0, 256><<<g256N, b512, 0, stream>>>(x,    nullptr, W1th, W1tl, b1, nullptr, nullptr, nullptr, buf0, nullptr, N_NODES);
  gemm_kernel<1, 256><<<g256N, b512, 0, stream>>>(buf0, nullptr, W2th, W2tl, b2, nullptr, nullptr, nullptr, buf1, nullptr, N_NODES);
  gemm_kernel<1, 256><<<g256N, b512, 0, stream>>>(buf1, nullptr, Woth, Wotl, bo, nullptr, nullptr, nullptr, buf0, nullptr, N_NODES);

  // U = h@P1top^T + P1b (buf0 -> buf1)
  gemm_kernel<2, 256><<<g256N, b512, 0, stream>>>(buf0, nullptr, PTth, PTtl, P1b, nullptr, nullptr, nullptr, buf1, nullptr, N_NODES);
  // V = h@P1bot^T (buf0 -> buf0 in place: BNT=512 keeps rows block-exclusive)
  gemm_kernel<2, 512><<<g512N, b1024, 0, stream>>>(buf0, nullptr, PBth, PBtl, nullptr, nullptr, nullptr, nullptr, buf0, nullptr, N_NODES);

  // fused edge scoring: A-row = relu(U[s]+V[d]); GEMM P2; relu; dot P3 -> scores
  gemm_kernel<3, 256><<<g256E, b512, 0, stream>>>(buf1, buf0, P2th, P2tl, P2b, pos_src, pos_dst, P3w, nullptr, out, E);
  gemm_kernel<3, 256><<<g256E, b512, 0, stream>>>(buf1, buf0, P2th, P2tl, P2b, neg_src, neg_dst, P3w, nullptr, out + E, E);
}